// Round 1
// baseline (47866.769 us; speedup 1.0000x reference)
//
#include <hip/hip_runtime.h>
#include <hip/hip_bf16.h>

// LSTMConvATTN — round 0: all-fp32 correctness baseline.
// Structure:
//   prep_misc : pack LSTM weights into streaming-friendly layout, bias=b_ih+b_hh, Veff=Wv_top+Wv_bot
//   eff_mat   : fold causal-conv into K/Q projections: B_tap = conv_w[:,:,tap]^T @ Wk_bot (+Wk_top), etc.
//   lstm_kernel: 64 WGs (1 per batch row) x 512 thr; h in LDS; streams packed W from L2 each step
//   gemm_panel: K (3-tap shifted, K-dim 1536), V (K-dim 512), Q (M=64) -> bf16 panels
//   attn_final: per-batch block: scores->softmax->ctx->Wfc->cat->out
// Workspace use ~89.7 MB.

typedef unsigned short u16;
typedef unsigned int u32;

#define KV_ 320
#define NWPACK (72 * 2048 * 8)

__device__ __forceinline__ u16 f2bf(float f) {
  __hip_bfloat16 h = __float2bfloat16(f);
  return __builtin_bit_cast(u16, h);
}
__device__ __forceinline__ float blo(u32 u) { return __builtin_bit_cast(float, u << 16); }
__device__ __forceinline__ float bhi(u32 u) { return __builtin_bit_cast(float, u & 0xffff0000u); }

// ---------------- prep ----------------
__global__ void prep_misc(const float* __restrict__ W_ih, const float* __restrict__ W_hh,
                          const float* __restrict__ b_ih, const float* __restrict__ b_hh,
                          const float* __restrict__ Wv,
                          float* __restrict__ Wpack, float* __restrict__ bias,
                          float* __restrict__ Veff) {
  int i = blockIdx.x * blockDim.x + threadIdx.x;
  if (i < NWPACK) {
    // layout [chunk c=0..71][gate g=0..2047][e=0..7]; c<8 -> x part (k=c*8+e), else h part
    int e = i & 7, g = (i >> 3) & 2047, c = i >> 14;
    float v = (c < 8) ? W_ih[g * 64 + c * 8 + e] : W_hh[g * 512 + (c - 8) * 8 + e];
    Wpack[i] = v;
  } else if (i < NWPACK + 2048) {
    int k = i - NWPACK;
    bias[k] = b_ih[k] + b_hh[k];
  } else if (i < NWPACK + 2048 + 262144) {
    int k = i - (NWPACK + 2048);
    Veff[k] = Wv[k] + Wv[262144 + k];
  }
}

// C[i][j] = (init?init[i][j]:0) + sum_o a[o*so + i*si] * Bsrc[o*512+j]   (i = blockIdx.x, j = tid)
__global__ void eff_mat(const float* __restrict__ a, int so, int si,
                        const float* __restrict__ Bsrc, const float* __restrict__ initm,
                        float* __restrict__ C) {
  int i = blockIdx.x, j = threadIdx.x;
  float acc = initm ? initm[i * 512 + j] : 0.f;
  for (int o = 0; o < 512; ++o)
    acc = fmaf(a[o * so + i * si], Bsrc[o * 512 + j], acc);
  C[i * 512 + j] = acc;
}

// ---------------- LSTM ----------------
__global__ __launch_bounds__(512) void lstm_kernel(
    const float* __restrict__ src, const float* __restrict__ Wpack,
    const float* __restrict__ bias, float* __restrict__ enc_out,
    float* __restrict__ h_n) {
  const int b = blockIdx.x, j = threadIdx.x;
  __shared__ __align__(16) float hx[576];  // [0..63]=x_t, [64..575]=h_{t-1}
  const float bi = bias[j], bff = bias[512 + j], bg = bias[1024 + j], bo = bias[1536 + j];
  float c = 0.f, hv = 0.f;
  hx[64 + j] = 0.f;
  const float* __restrict__ srow = src + (size_t)b * (1024 * 64);
  for (int t = 0; t < 1024; ++t) {
    if (j < 64) hx[j] = srow[t * 64 + j];
    __syncthreads();
    float ai = bi, af = bff, ag = bg, ao = bo;
    const float4* __restrict__ h4 = (const float4*)hx;
#pragma unroll 2
    for (int cc = 0; cc < 72; ++cc) {
      const float4* __restrict__ wb = (const float4*)Wpack + (size_t)cc * 4096;
      float4 x0 = h4[cc * 2], x1 = h4[cc * 2 + 1];
      float4 wi0 = wb[j * 2], wi1 = wb[j * 2 + 1];
      float4 wf0 = wb[(512 + j) * 2], wf1 = wb[(512 + j) * 2 + 1];
      float4 wg0 = wb[(1024 + j) * 2], wg1 = wb[(1024 + j) * 2 + 1];
      float4 wo0 = wb[(1536 + j) * 2], wo1 = wb[(1536 + j) * 2 + 1];
      ai += wi0.x * x0.x + wi0.y * x0.y + wi0.z * x0.z + wi0.w * x0.w
          + wi1.x * x1.x + wi1.y * x1.y + wi1.z * x1.z + wi1.w * x1.w;
      af += wf0.x * x0.x + wf0.y * x0.y + wf0.z * x0.z + wf0.w * x0.w
          + wf1.x * x1.x + wf1.y * x1.y + wf1.z * x1.z + wf1.w * x1.w;
      ag += wg0.x * x0.x + wg0.y * x0.y + wg0.z * x0.z + wg0.w * x0.w
          + wg1.x * x1.x + wg1.y * x1.y + wg1.z * x1.z + wg1.w * x1.w;
      ao += wo0.x * x0.x + wo0.y * x0.y + wo0.z * x0.z + wo0.w * x0.w
          + wo1.x * x1.x + wo1.y * x1.y + wo1.z * x1.z + wo1.w * x1.w;
    }
    float iv = 1.f / (1.f + expf(-ai));
    float fv = 1.f / (1.f + expf(-af));
    float gv = tanhf(ag);
    float ov = 1.f / (1.f + expf(-ao));
    c = fv * c + iv * gv;
    hv = ov * tanhf(c);
    __syncthreads();  // everyone done reading h before overwrite
    hx[64 + j] = hv;
    if (t < KV_) enc_out[((size_t)b * KV_ + t) * 512 + j] = hv;
  }
  h_n[(size_t)b * 512 + j] = hv;
}

// ---------------- panel GEMM (fp32 in, bf16 out) ----------------
// C[r][n] = sum_seg sum_k A[r+seg-2][k] * Bm[seg*512+k][n]  (+bias), masked at batch-local t<2-seg
__global__ __launch_bounds__(256) void gemm_panel(
    const float* __restrict__ A, int M, int nseg, int shifted,
    const float* __restrict__ Bm, const float* __restrict__ bias,
    u16* __restrict__ C) {
  __shared__ float As[16][72];
  __shared__ float Bs[16][64];
  const int tid = threadIdx.x;
  const int nx = blockIdx.x, my = blockIdx.y;
  const int tx = tid & 15, ty = tid >> 4;
  const int m0 = ty * 4, n0 = tx * 4;
  const int lr = tid >> 2, lc = (tid & 3) * 4;
  const int kr = tid >> 4, nc = (tid & 15) * 4;
  float acc[4][4] = {};
  const int KK = nseg * 512;
  const int rA = my * 64 + lr;
  const int tloc = rA % KV_;
  for (int kk = 0; kk < KK; kk += 16) {
    const int seg = kk >> 9, k0 = kk & 511;
    float4 av = make_float4(0.f, 0.f, 0.f, 0.f);
    if (rA < M) {
      int arow = rA, valid = 1;
      if (shifted) { arow = rA + seg - 2; valid = (tloc + seg - 2) >= 0; }
      if (valid) av = *(const float4*)&A[(size_t)arow * 512 + k0 + lc];
    }
    As[lc + 0][lr] = av.x; As[lc + 1][lr] = av.y;
    As[lc + 2][lr] = av.z; As[lc + 3][lr] = av.w;
    *(float4*)&Bs[kr][nc] = *(const float4*)&Bm[(size_t)(kk + kr) * 512 + nx * 64 + nc];
    __syncthreads();
#pragma unroll
    for (int k = 0; k < 16; ++k) {
      float4 A4 = *(const float4*)&As[k][m0];
      float4 B4 = *(const float4*)&Bs[k][n0];
      float ar[4] = {A4.x, A4.y, A4.z, A4.w};
      float br[4] = {B4.x, B4.y, B4.z, B4.w};
#pragma unroll
      for (int ii = 0; ii < 4; ++ii)
#pragma unroll
        for (int jj = 0; jj < 4; ++jj)
          acc[ii][jj] = fmaf(ar[ii], br[jj], acc[ii][jj]);
    }
    __syncthreads();
  }
#pragma unroll
  for (int ii = 0; ii < 4; ++ii) {
    int r = my * 64 + m0 + ii;
    if (r < M) {
#pragma unroll
      for (int jj = 0; jj < 4; ++jj) {
        int col = nx * 64 + n0 + jj;
        float v = acc[ii][jj] + (bias ? bias[col] : 0.f);
        C[(size_t)r * 512 + col] = f2bf(v);
      }
    }
  }
}

// ---------------- attention + head ----------------
__global__ __launch_bounds__(256) void attn_final(
    const u16* __restrict__ Qp, const u16* __restrict__ Kp, const u16* __restrict__ Vp,
    const float* __restrict__ h_n, const float* __restrict__ Wfc,
    const float* __restrict__ catW, const float* __restrict__ catb,
    const float* __restrict__ outW, float* __restrict__ out) {
  const int b = blockIdx.x, tid = threadIdx.x;
  __shared__ float sc[8 * KV_];
  __shared__ float ctx[512];
  __shared__ float av[512];
  __shared__ float ha[64];
  __shared__ uint4 qs[64];
  if (tid < 64) qs[tid] = ((const uint4*)(Qp + (size_t)b * 512))[tid];
  __syncthreads();
  for (int idx = tid; idx < 8 * KV_; idx += 256) {
    int h = idx / KV_, t = idx % KV_;
    const uint4* kr4 = (const uint4*)(Kp + ((size_t)(b * KV_ + t)) * 512 + h * 64);
    float s = 0.f;
#pragma unroll
    for (int u = 0; u < 8; ++u) {
      uint4 kv = kr4[u]; uint4 qv = qs[h * 8 + u];
      s += blo(kv.x) * blo(qv.x) + bhi(kv.x) * bhi(qv.x)
         + blo(kv.y) * blo(qv.y) + bhi(kv.y) * bhi(qv.y)
         + blo(kv.z) * blo(qv.z) + bhi(kv.z) * bhi(qv.z)
         + blo(kv.w) * blo(qv.w) + bhi(kv.w) * bhi(qv.w);
    }
    sc[h * KV_ + t] = s * 0.125f;
  }
  __syncthreads();
  {
    int h = tid >> 5, l = tid & 31;
    float m = -1e30f;
    for (int t = l; t < KV_; t += 32) m = fmaxf(m, sc[h * KV_ + t]);
    for (int o = 16; o; o >>= 1) m = fmaxf(m, __shfl_xor(m, o, 32));
    float sum = 0.f;
    for (int t = l; t < KV_; t += 32) { float e = expf(sc[h * KV_ + t] - m); sc[h * KV_ + t] = e; sum += e; }
    for (int o = 16; o; o >>= 1) sum += __shfl_xor(sum, o, 32);
    float inv = 1.f / sum;
    for (int t = l; t < KV_; t += 32) sc[h * KV_ + t] *= inv;
  }
  __syncthreads();
  for (int j = tid; j < 512; j += 256) {
    int h = j >> 6, d = j & 63;
    const u16* vp = Vp + (size_t)(b * KV_) * 512 + h * 64 + d;
    float a = 0.f;
    for (int t = 0; t < KV_; ++t)
      a = fmaf(sc[h * KV_ + t], blo((u32)vp[(size_t)t * 512] << 16 >> 16 ? (u32)vp[(size_t)t * 512] : (u32)vp[(size_t)t * 512]), a);
    ctx[j] = a;
  }
  __syncthreads();
  for (int j = tid; j < 512; j += 256) {
    float a = 0.f;
    for (int i = 0; i < 512; ++i) a = fmaf(ctx[i], Wfc[(size_t)i * 512 + j], a);
    av[j] = a;
  }
  __syncthreads();
  if (tid < 64) {
    float a = catb[tid];
    const float* hb = h_n + (size_t)b * 512;
    for (int i = 0; i < 512; ++i) a = fmaf(hb[i], catW[i * 64 + tid], a);
    for (int i = 0; i < 512; ++i) a = fmaf(av[i], catW[(512 + i) * 64 + tid], a);
    ha[tid] = a;
  }
  __syncthreads();
  if (tid < 64) {
    float v = ha[tid] * outW[tid];
    for (int o = 32; o; o >>= 1) v += __shfl_xor(v, o, 64);
    if (tid == 0) out[b] = v;
  }
}

extern "C" void kernel_launch(void* const* d_in, const int* in_sizes, int n_in,
                              void* d_out, int out_size, void* d_ws, size_t ws_size,
                              hipStream_t stream) {
  const float* src   = (const float*)d_in[0];
  const float* W_ih  = (const float*)d_in[2];
  const float* W_hh  = (const float*)d_in[3];
  const float* b_ih  = (const float*)d_in[4];
  const float* b_hh  = (const float*)d_in[5];
  const float* convw = (const float*)d_in[6];
  const float* convb = (const float*)d_in[7];
  const float* Wq    = (const float*)d_in[8];
  const float* Wk    = (const float*)d_in[9];
  const float* Wv    = (const float*)d_in[10];
  const float* Wfc   = (const float*)d_in[11];
  const float* catW  = (const float*)d_in[12];
  const float* catb  = (const float*)d_in[13];
  const float* outW  = (const float*)d_in[14];
  float* out = (float*)d_out;

  char* w = (char*)d_ws;
  float* Wpack = (float*)w;  w += (size_t)NWPACK * 4;
  float* bias  = (float*)w;  w += 2048 * 4;
  float* Beff  = (float*)w;  w += (size_t)3 * 512 * 512 * 4;
  float* Qeff  = (float*)w;  w += (size_t)512 * 512 * 4;
  float* Veff  = (float*)w;  w += (size_t)512 * 512 * 4;
  float* kb    = (float*)w;  w += 512 * 4;
  float* qb    = (float*)w;  w += 512 * 4;
  float* h_n   = (float*)w;  w += (size_t)64 * 512 * 4;
  float* enc   = (float*)w;  w += (size_t)64 * KV_ * 512 * 4;
  u16*   Kp    = (u16*)w;    w += (size_t)64 * KV_ * 512 * 2;
  u16*   Vp    = (u16*)w;    w += (size_t)64 * KV_ * 512 * 2;
  u16*   Qp    = (u16*)w;    w += (size_t)64 * 512 * 2;

  int prepN = NWPACK + 2048 + 262144;
  prep_misc<<<(prepN + 255) / 256, 256, 0, stream>>>(W_ih, W_hh, b_ih, b_hh, Wv, Wpack, bias, Veff);
  // folded conv->projection matrices
  eff_mat<<<512, 512, 0, stream>>>(convw + 0, 1536, 3, Wk + 262144, nullptr, Beff);
  eff_mat<<<512, 512, 0, stream>>>(convw + 1, 1536, 3, Wk + 262144, nullptr, Beff + 262144);
  eff_mat<<<512, 512, 0, stream>>>(convw + 2, 1536, 3, Wk + 262144, Wk, Beff + 524288);
  eff_mat<<<512, 512, 0, stream>>>(convw + 2, 1536, 3, Wq + 262144, Wq, Qeff);
  eff_mat<<<1, 512, 0, stream>>>(convb, 1, 0, Wk + 262144, nullptr, kb);
  eff_mat<<<1, 512, 0, stream>>>(convb, 1, 0, Wq + 262144, nullptr, qb);
  lstm_kernel<<<64, 512, 0, stream>>>(src, Wpack, bias, enc, h_n);
  gemm_panel<<<dim3(8, KV_), 256, 0, stream>>>(enc, 64 * KV_, 3, 1, Beff, kb, Kp);
  gemm_panel<<<dim3(8, KV_), 256, 0, stream>>>(enc, 64 * KV_, 1, 0, Veff, nullptr, Vp);
  gemm_panel<<<dim3(8, 1), 256, 0, stream>>>(h_n, 64, 1, 0, Qeff, qb, Qp);
  attn_final<<<64, 256, 0, stream>>>(Qp, Kp, Vp, h_n, Wfc, catW, catb, outW, out);
}

// Round 2
// 22877.457 us; speedup vs baseline: 2.0923x; 2.0923x over previous
//
#include <hip/hip_runtime.h>
#include <hip/hip_bf16.h>

// LSTMConvATTN — round 1: weight-resident synced LSTM.
//   16 sets x 16 WGs; set s handles batches [4s,4s+4); WG holds 128 gate rows
//   (32 hidden units x 4 gates) of W_hh in 128 VGPRs/thread + W_ih in 16.
//   Per step: gather h (agent-scope atomic loads, L3-coherent) -> LDS (XOR-
//   swizzled) -> 576 FMA/lane -> shfl reduce over 16 k-lanes -> gate update
//   -> agent-scope atomic h stores -> per-(set,step) counter barrier.
//   Cooperative launch guarantees co-residency of all 256 WGs.

typedef unsigned short u16;
typedef unsigned int u32;

#define KV_ 320
#define GSET 16
#define NSET 16
#define BSET 4

__device__ __forceinline__ u16 f2bf(float f) {
  __hip_bfloat16 h = __float2bfloat16(f);
  return __builtin_bit_cast(u16, h);
}
__device__ __forceinline__ float blo(u32 u) { return __builtin_bit_cast(float, u << 16); }
__device__ __forceinline__ float bhi(u32 u) { return __builtin_bit_cast(float, u & 0xffff0000u); }

// ---------------- prep ----------------
__global__ void veff_kernel(const float* __restrict__ Wv, float* __restrict__ Veff) {
  int i = blockIdx.x * blockDim.x + threadIdx.x;
  if (i < 262144) Veff[i] = Wv[i] + Wv[262144 + i];
}

// C[i][j] = (init?init[i][j]:0) + sum_o a[o*so + i*si] * Bsrc[o*512+j]
__global__ void eff_mat(const float* __restrict__ a, int so, int si,
                        const float* __restrict__ Bsrc, const float* __restrict__ initm,
                        float* __restrict__ C) {
  int i = blockIdx.x, j = threadIdx.x;
  float acc = initm ? initm[i * 512 + j] : 0.f;
  for (int o = 0; o < 512; ++o)
    acc = fmaf(a[o * so + i * si], Bsrc[o * 512 + j], acc);
  C[i * 512 + j] = acc;
}

// ---------------- LSTM (weight-resident, synced) ----------------
__global__ __launch_bounds__(512, 2) void lstm_sync(
    const float* __restrict__ src,
    const float* __restrict__ W_ih, const float* __restrict__ W_hh,
    const float* __restrict__ b_ih, const float* __restrict__ b_hh,
    float* __restrict__ h_glob,   // [NSET][2][512][BSET]
    u32* __restrict__ cnt,        // [NSET][1024]
    float* __restrict__ enc_out,  // [64][KV_][512]
    float* __restrict__ h_n) {    // [64][512]
  const int tid = threadIdx.x;
  const int bid = blockIdx.x;
  // XCD-friendly set mapping: set s = WGs with blockIdx%8==s%8 (perf heuristic only)
  const int xcd = bid & 7, jj = bid >> 3;
  const int s = xcd + 8 * (jj >> 4);
  const int wg = jj & 15;
  const int hb = wg * 32;          // hidden base of this WG's 32 units
  const int bg0 = s * BSET;

  const int rg = tid >> 4;         // 0..31 : row group (4 rows each)
  const int ksub = tid & 15;       // 0..15 : k sub-range (32 k's each)
  const int sw = (ksub & 7) << 2;  // LDS bank swizzle (xor bits 2..4)

  __shared__ float hl[4 * 512];    // [b][k] (k swizzled), fp32
  __shared__ float xl[4 * 64];     // [b][k]
  __shared__ float gb[128 * 4];    // [r_local][b]

  // ---- load resident weights (physical order matches swizzled LDS reads) ----
  float wreg[4][32];
  float wxreg[4][4];
#pragma unroll
  for (int rr = 0; rr < 4; ++rr) {
    const int rl = rg * 4 + rr;                      // 0..127
    const int grow = ((rl >> 5) << 9) + hb + (rl & 31);
    const float* wrow = W_hh + (size_t)grow * 512 + (ksub << 5);
#pragma unroll
    for (int j4 = 0; j4 < 8; ++j4) {
      const int joff = (j4 << 2) ^ sw;
      const float4 wv = *(const float4*)(wrow + joff);
      wreg[rr][(j4 << 2) + 0] = wv.x;
      wreg[rr][(j4 << 2) + 1] = wv.y;
      wreg[rr][(j4 << 2) + 2] = wv.z;
      wreg[rr][(j4 << 2) + 3] = wv.w;
    }
    const float4 wx = *(const float4*)(W_ih + (size_t)grow * 64 + (ksub << 2));
    wxreg[rr][0] = wx.x; wxreg[rr][1] = wx.y; wxreg[rr][2] = wx.z; wxreg[rr][3] = wx.w;
  }

  // ---- update-thread state (tid<128: one (u,b) pair each) ----
  float bI = 0.f, bF = 0.f, bG = 0.f, bO = 0.f, cc = 0.f;
  const int ub = tid >> 2, bb = tid & 3;
  if (tid < 128) {
    const int r0 = hb + ub;
    bI = b_ih[r0] + b_hh[r0];
    bF = b_ih[512 + r0] + b_hh[512 + r0];
    bG = b_ih[1024 + r0] + b_hh[1024 + r0];
    bO = b_ih[1536 + r0] + b_hh[1536 + r0];
  }

  float* hg = h_glob + s * (2 * 2048);
  u32* cset = cnt + s * 1024;
  const float4* hl4 = (const float4*)hl;
  const float4* xl4 = (const float4*)xl;
  const int hbase = ksub << 3;

  for (int t = 0; t < 1024; ++t) {
    // phase 1: wait for all WGs of the set to finish step t-1
    if (t > 0) {
      if (tid == 0) {
        while (__hip_atomic_load(&cset[t - 1], __ATOMIC_ACQUIRE, __HIP_MEMORY_SCOPE_AGENT) < GSET) {
          __builtin_amdgcn_s_sleep(2);
        }
      }
      __syncthreads();
    }
    // phase 2: gather h (L3-coherent) and x into LDS
    {
      const int k0 = tid;
      const int kp0 = k0 ^ (((k0 >> 5) & 7) << 2);
      if (t == 0) {
        hl[kp0] = 0.f; hl[512 + kp0] = 0.f; hl[1024 + kp0] = 0.f; hl[1536 + kp0] = 0.f;
      } else {
        const float* hgp = hg + (((t - 1) & 1) << 11) + (k0 << 2);
        const float v0 = __hip_atomic_load(hgp + 0, __ATOMIC_RELAXED, __HIP_MEMORY_SCOPE_AGENT);
        const float v1 = __hip_atomic_load(hgp + 1, __ATOMIC_RELAXED, __HIP_MEMORY_SCOPE_AGENT);
        const float v2 = __hip_atomic_load(hgp + 2, __ATOMIC_RELAXED, __HIP_MEMORY_SCOPE_AGENT);
        const float v3 = __hip_atomic_load(hgp + 3, __ATOMIC_RELAXED, __HIP_MEMORY_SCOPE_AGENT);
        hl[kp0] = v0; hl[512 + kp0] = v1; hl[1024 + kp0] = v2; hl[1536 + kp0] = v3;
      }
      if (tid < 256) {
        const int b = tid >> 6, k = tid & 63;
        xl[(b << 6) + k] = src[((size_t)(bg0 + b) * 1024 + t) * 64 + k];
      }
    }
    __syncthreads();
    // phase 3: matvec (resident weights x LDS h)
    float acc[4][4];
#pragma unroll
    for (int rr = 0; rr < 4; ++rr)
#pragma unroll
      for (int b = 0; b < 4; ++b) acc[rr][b] = 0.f;
#pragma unroll
    for (int j4 = 0; j4 < 8; ++j4) {
      const float4 h0 = hl4[hbase + j4];
      const float4 h1 = hl4[128 + hbase + j4];
      const float4 h2 = hl4[256 + hbase + j4];
      const float4 h3 = hl4[384 + hbase + j4];
#pragma unroll
      for (int rr = 0; rr < 4; ++rr) {
        const float w0 = wreg[rr][(j4 << 2) + 0], w1 = wreg[rr][(j4 << 2) + 1];
        const float w2 = wreg[rr][(j4 << 2) + 2], w3 = wreg[rr][(j4 << 2) + 3];
        acc[rr][0] = fmaf(w0, h0.x, fmaf(w1, h0.y, fmaf(w2, h0.z, fmaf(w3, h0.w, acc[rr][0]))));
        acc[rr][1] = fmaf(w0, h1.x, fmaf(w1, h1.y, fmaf(w2, h1.z, fmaf(w3, h1.w, acc[rr][1]))));
        acc[rr][2] = fmaf(w0, h2.x, fmaf(w1, h2.y, fmaf(w2, h2.z, fmaf(w3, h2.w, acc[rr][2]))));
        acc[rr][3] = fmaf(w0, h3.x, fmaf(w1, h3.y, fmaf(w2, h3.z, fmaf(w3, h3.w, acc[rr][3]))));
      }
    }
    {
      const float4 x0 = xl4[ksub];
      const float4 x1 = xl4[16 + ksub];
      const float4 x2 = xl4[32 + ksub];
      const float4 x3 = xl4[48 + ksub];
#pragma unroll
      for (int rr = 0; rr < 4; ++rr) {
        const float w0 = wxreg[rr][0], w1 = wxreg[rr][1], w2 = wxreg[rr][2], w3 = wxreg[rr][3];
        acc[rr][0] = fmaf(w0, x0.x, fmaf(w1, x0.y, fmaf(w2, x0.z, fmaf(w3, x0.w, acc[rr][0]))));
        acc[rr][1] = fmaf(w0, x1.x, fmaf(w1, x1.y, fmaf(w2, x1.z, fmaf(w3, x1.w, acc[rr][1]))));
        acc[rr][2] = fmaf(w0, x2.x, fmaf(w1, x2.y, fmaf(w2, x2.z, fmaf(w3, x2.w, acc[rr][2]))));
        acc[rr][3] = fmaf(w0, x3.x, fmaf(w1, x3.y, fmaf(w2, x3.z, fmaf(w3, x3.w, acc[rr][3]))));
      }
    }
    // reduce over 16 k-lanes
#pragma unroll
    for (int off = 1; off < 16; off <<= 1) {
#pragma unroll
      for (int rr = 0; rr < 4; ++rr) {
#pragma unroll
        for (int b = 0; b < 4; ++b)
          acc[rr][b] += __shfl_xor(acc[rr][b], off, 16);
      }
    }
    if (ksub == 0) {
#pragma unroll
      for (int rr = 0; rr < 4; ++rr)
        ((float4*)gb)[rg * 4 + rr] = make_float4(acc[rr][0], acc[rr][1], acc[rr][2], acc[rr][3]);
    }
    __syncthreads();
    // phase 4: gate update + h publication
    if (tid < 128) {
      const float gi = gb[(ub) * 4 + bb] + bI;
      const float gf = gb[(32 + ub) * 4 + bb] + bF;
      const float gg = gb[(64 + ub) * 4 + bb] + bG;
      const float go = gb[(96 + ub) * 4 + bb] + bO;
      const float iv = 1.f / (1.f + expf(-gi));
      const float fv = 1.f / (1.f + expf(-gf));
      const float gv = tanhf(gg);
      const float ov = 1.f / (1.f + expf(-go));
      cc = fv * cc + iv * gv;
      const float hv = ov * tanhf(cc);
      __hip_atomic_store(&hg[((t & 1) << 11) + ((hb + ub) << 2) + bb], hv,
                         __ATOMIC_RELAXED, __HIP_MEMORY_SCOPE_AGENT);
      if (t < KV_) enc_out[((size_t)(bg0 + bb) * KV_ + t) * 512 + hb + ub] = hv;
      if (t == 1023) h_n[(size_t)(bg0 + bb) * 512 + hb + ub] = hv;
    }
    __syncthreads();  // per-wave vmcnt drain before barrier -> stores committed
    // phase 5: arrive
    if (t < 1023 && tid == 0) {
      __hip_atomic_fetch_add(&cset[t], 1u, __ATOMIC_RELEASE, __HIP_MEMORY_SCOPE_AGENT);
    }
  }
}

// ---------------- panel GEMM (fp32 in, bf16 out) ----------------
__global__ __launch_bounds__(256) void gemm_panel(
    const float* __restrict__ A, int M, int nseg, int shifted,
    const float* __restrict__ Bm, const float* __restrict__ bias,
    u16* __restrict__ C) {
  __shared__ float As[16][72];
  __shared__ float Bs[16][64];
  const int tid = threadIdx.x;
  const int nx = blockIdx.x, my = blockIdx.y;
  const int tx = tid & 15, ty = tid >> 4;
  const int m0 = ty * 4, n0 = tx * 4;
  const int lr = tid >> 2, lc = (tid & 3) * 4;
  const int kr = tid >> 4, nc = (tid & 15) * 4;
  float acc[4][4] = {};
  const int KK = nseg * 512;
  const int rA = my * 64 + lr;
  const int tloc = rA % KV_;
  for (int kk = 0; kk < KK; kk += 16) {
    const int seg = kk >> 9, k0 = kk & 511;
    float4 av = make_float4(0.f, 0.f, 0.f, 0.f);
    if (rA < M) {
      int arow = rA, valid = 1;
      if (shifted) { arow = rA + seg - 2; valid = (tloc + seg - 2) >= 0; }
      if (valid) av = *(const float4*)&A[(size_t)arow * 512 + k0 + lc];
    }
    As[lc + 0][lr] = av.x; As[lc + 1][lr] = av.y;
    As[lc + 2][lr] = av.z; As[lc + 3][lr] = av.w;
    *(float4*)&Bs[kr][nc] = *(const float4*)&Bm[(size_t)(kk + kr) * 512 + nx * 64 + nc];
    __syncthreads();
#pragma unroll
    for (int k = 0; k < 16; ++k) {
      float4 A4 = *(const float4*)&As[k][m0];
      float4 B4 = *(const float4*)&Bs[k][n0];
      float ar[4] = {A4.x, A4.y, A4.z, A4.w};
      float br[4] = {B4.x, B4.y, B4.z, B4.w};
#pragma unroll
      for (int ii = 0; ii < 4; ++ii)
#pragma unroll
        for (int jj = 0; jj < 4; ++jj)
          acc[ii][jj] = fmaf(ar[ii], br[jj], acc[ii][jj]);
    }
    __syncthreads();
  }
#pragma unroll
  for (int ii = 0; ii < 4; ++ii) {
    int r = my * 64 + m0 + ii;
    if (r < M) {
#pragma unroll
      for (int jj = 0; jj < 4; ++jj) {
        int col = nx * 64 + n0 + jj;
        float v = acc[ii][jj] + (bias ? bias[col] : 0.f);
        C[(size_t)r * 512 + col] = f2bf(v);
      }
    }
  }
}

// ---------------- attention + head ----------------
__global__ __launch_bounds__(256) void attn_final(
    const u16* __restrict__ Qp, const u16* __restrict__ Kp, const u16* __restrict__ Vp,
    const float* __restrict__ h_n, const float* __restrict__ Wfc,
    const float* __restrict__ catW, const float* __restrict__ catb,
    const float* __restrict__ outW, float* __restrict__ out) {
  const int b = blockIdx.x, tid = threadIdx.x;
  __shared__ float sc[8 * KV_];
  __shared__ float ctx[512];
  __shared__ float av[512];
  __shared__ float ha[64];
  __shared__ uint4 qs[64];
  if (tid < 64) qs[tid] = ((const uint4*)(Qp + (size_t)b * 512))[tid];
  __syncthreads();
  for (int idx = tid; idx < 8 * KV_; idx += 256) {
    int h = idx / KV_, t = idx % KV_;
    const uint4* kr4 = (const uint4*)(Kp + ((size_t)(b * KV_ + t)) * 512 + h * 64);
    float s = 0.f;
#pragma unroll
    for (int u = 0; u < 8; ++u) {
      uint4 kv = kr4[u]; uint4 qv = qs[h * 8 + u];
      s += blo(kv.x) * blo(qv.x) + bhi(kv.x) * bhi(qv.x)
         + blo(kv.y) * blo(qv.y) + bhi(kv.y) * bhi(qv.y)
         + blo(kv.z) * blo(qv.z) + bhi(kv.z) * bhi(qv.z)
         + blo(kv.w) * blo(qv.w) + bhi(kv.w) * bhi(qv.w);
    }
    sc[h * KV_ + t] = s * 0.125f;
  }
  __syncthreads();
  {
    int h = tid >> 5, l = tid & 31;
    float m = -1e30f;
    for (int t = l; t < KV_; t += 32) m = fmaxf(m, sc[h * KV_ + t]);
    for (int o = 16; o; o >>= 1) m = fmaxf(m, __shfl_xor(m, o, 32));
    float sum = 0.f;
    for (int t = l; t < KV_; t += 32) { float e = expf(sc[h * KV_ + t] - m); sc[h * KV_ + t] = e; sum += e; }
    for (int o = 16; o; o >>= 1) sum += __shfl_xor(sum, o, 32);
    float inv = 1.f / sum;
    for (int t = l; t < KV_; t += 32) sc[h * KV_ + t] *= inv;
  }
  __syncthreads();
  for (int j = tid; j < 512; j += 256) {
    int h = j >> 6, d = j & 63;
    const u16* vp = Vp + (size_t)(b * KV_) * 512 + h * 64 + d;
    float a = 0.f;
    for (int t = 0; t < KV_; ++t)
      a = fmaf(sc[h * KV_ + t], blo((u32)vp[(size_t)t * 512]), a);
    ctx[j] = a;
  }
  __syncthreads();
  for (int j = tid; j < 512; j += 256) {
    float a = 0.f;
    for (int i = 0; i < 512; ++i) a = fmaf(ctx[i], Wfc[(size_t)i * 512 + j], a);
    av[j] = a;
  }
  __syncthreads();
  if (tid < 64) {
    float a = catb[tid];
    const float* hb = h_n + (size_t)b * 512;
    for (int i = 0; i < 512; ++i) a = fmaf(hb[i], catW[i * 64 + tid], a);
    for (int i = 0; i < 512; ++i) a = fmaf(av[i], catW[(512 + i) * 64 + tid], a);
    ha[tid] = a;
  }
  __syncthreads();
  if (tid < 64) {
    float v = ha[tid] * outW[tid];
    for (int o = 32; o; o >>= 1) v += __shfl_xor(v, o, 64);
    if (tid == 0) out[b] = v;
  }
}

extern "C" void kernel_launch(void* const* d_in, const int* in_sizes, int n_in,
                              void* d_out, int out_size, void* d_ws, size_t ws_size,
                              hipStream_t stream) {
  const float* src   = (const float*)d_in[0];
  const float* W_ih  = (const float*)d_in[2];
  const float* W_hh  = (const float*)d_in[3];
  const float* b_ih  = (const float*)d_in[4];
  const float* b_hh  = (const float*)d_in[5];
  const float* convw = (const float*)d_in[6];
  const float* convb = (const float*)d_in[7];
  const float* Wq    = (const float*)d_in[8];
  const float* Wk    = (const float*)d_in[9];
  const float* Wv    = (const float*)d_in[10];
  const float* Wfc   = (const float*)d_in[11];
  const float* catW  = (const float*)d_in[12];
  const float* catb  = (const float*)d_in[13];
  const float* outW  = (const float*)d_in[14];
  float* out = (float*)d_out;

  char* w = (char*)d_ws;
  float* Beff  = (float*)w;  w += (size_t)3 * 512 * 512 * 4;
  float* Qeff  = (float*)w;  w += (size_t)512 * 512 * 4;
  float* Veff  = (float*)w;  w += (size_t)512 * 512 * 4;
  float* kb    = (float*)w;  w += 512 * 4;
  float* qb    = (float*)w;  w += 512 * 4;
  float* h_n   = (float*)w;  w += (size_t)64 * 512 * 4;
  float* enc   = (float*)w;  w += (size_t)64 * KV_ * 512 * 4;
  u16*   Kp    = (u16*)w;    w += (size_t)64 * KV_ * 512 * 2;
  u16*   Vp    = (u16*)w;    w += (size_t)64 * KV_ * 512 * 2;
  u16*   Qp    = (u16*)w;    w += (size_t)64 * 512 * 2;
  float* h_glob = (float*)w; w += (size_t)NSET * 2 * 2048 * 4;
  u32*   cnt   = (u32*)w;    w += (size_t)NSET * 1024 * 4;

  veff_kernel<<<1024, 256, 0, stream>>>(Wv, Veff);
  eff_mat<<<512, 512, 0, stream>>>(convw + 0, 1536, 3, Wk + 262144, nullptr, Beff);
  eff_mat<<<512, 512, 0, stream>>>(convw + 1, 1536, 3, Wk + 262144, nullptr, Beff + 262144);
  eff_mat<<<512, 512, 0, stream>>>(convw + 2, 1536, 3, Wk + 262144, Wk, Beff + 524288);
  eff_mat<<<512, 512, 0, stream>>>(convw + 2, 1536, 3, Wq + 262144, Wq, Qeff);
  eff_mat<<<1, 512, 0, stream>>>(convb, 1, 0, Wk + 262144, nullptr, kb);
  eff_mat<<<1, 512, 0, stream>>>(convb, 1, 0, Wq + 262144, nullptr, qb);

  hipMemsetAsync((void*)cnt, 0, (size_t)NSET * 1024 * 4, stream);
  {
    const float* a_src = src; const float* a_wih = W_ih; const float* a_whh = W_hh;
    const float* a_bih = b_ih; const float* a_bhh = b_hh;
    float* a_hg = h_glob; u32* a_cnt = cnt; float* a_enc = enc; float* a_hn = h_n;
    void* args[] = {(void*)&a_src, (void*)&a_wih, (void*)&a_whh, (void*)&a_bih,
                    (void*)&a_bhh, (void*)&a_hg, (void*)&a_cnt, (void*)&a_enc, (void*)&a_hn};
    hipLaunchCooperativeKernel(lstm_sync, dim3(256), dim3(512), args, 0, stream);
  }

  gemm_panel<<<dim3(8, KV_), 256, 0, stream>>>(enc, 64 * KV_, 3, 1, Beff, kb, Kp);
  gemm_panel<<<dim3(8, KV_), 256, 0, stream>>>(enc, 64 * KV_, 1, 0, Veff, nullptr, Vp);
  gemm_panel<<<dim3(8, 1), 256, 0, stream>>>(h_n, 64, 1, 0, Qeff, qb, Qp);
  attn_final<<<64, 256, 0, stream>>>(Qp, Kp, Vp, h_n, Wfc, catW, catb, outW, out);
}

// Round 3
// 22637.938 us; speedup vs baseline: 2.1144x; 1.0106x over previous
//
#include <hip/hip_runtime.h>
#include <hip/hip_bf16.h>

// LSTMConvATTN — round 2: weight-resident synced LSTM, patched.
//   vs round 1: (a) h exchange via coalesced dwordx4 sc0/sc1 bulk loads
//   (was per-element atomic loads -> 64B line per 4B = 34GB fetch);
//   (b) LDS read-side XOR swizzle + matching weight-register permutation
//   (was 16-way bank conflict, 1.9e9 conflict cycles);
//   (c) padded sync counters (64B/counter) + x(t+1) LDS double-buffer
//   prefetched under the poll wait.

typedef unsigned short u16;
typedef unsigned int u32;

#define KV_ 320
#define GSET 16
#define NSET 16
#define BSET 4
#define CNT_STRIDE 16  // u32s per counter (64B line)

__device__ __forceinline__ u16 f2bf(float f) {
  __hip_bfloat16 h = __float2bfloat16(f);
  return __builtin_bit_cast(u16, h);
}
__device__ __forceinline__ float blo(u32 u) { return __builtin_bit_cast(float, u << 16); }
__device__ __forceinline__ float bhi(u32 u) { return __builtin_bit_cast(float, u & 0xffff0000u); }

// coherent (L1/L2-bypass) bulk load: 16B per lane, waits inside
__device__ __forceinline__ float4 load_f4_coherent(const float* p) {
  float4 r;
  asm volatile("global_load_dwordx4 %0, %1, off sc0 sc1\n\t"
               "s_waitcnt vmcnt(0)"
               : "=v"(r) : "v"(p) : "memory");
  return r;
}
__device__ __forceinline__ void store_f_coherent(float* p, float v) {
  asm volatile("global_store_dword %0, %1, off sc0 sc1" :: "v"(p), "v"(v) : "memory");
}

// ---------------- prep ----------------
__global__ void veff_kernel(const float* __restrict__ Wv, float* __restrict__ Veff) {
  int i = blockIdx.x * blockDim.x + threadIdx.x;
  if (i < 262144) Veff[i] = Wv[i] + Wv[262144 + i];
}

// C[i][j] = (init?init[i][j]:0) + sum_o a[o*so + i*si] * Bsrc[o*512+j]
__global__ void eff_mat(const float* __restrict__ a, int so, int si,
                        const float* __restrict__ Bsrc, const float* __restrict__ initm,
                        float* __restrict__ C) {
  int i = blockIdx.x, j = threadIdx.x;
  float acc = initm ? initm[i * 512 + j] : 0.f;
  for (int o = 0; o < 512; ++o)
    acc = fmaf(a[o * so + i * si], Bsrc[o * 512 + j], acc);
  C[i * 512 + j] = acc;
}

// ---------------- LSTM (weight-resident, synced) ----------------
__global__ __launch_bounds__(512, 2) void lstm_sync(
    const float* __restrict__ src,
    const float* __restrict__ W_ih, const float* __restrict__ W_hh,
    const float* __restrict__ b_ih, const float* __restrict__ b_hh,
    float* __restrict__ h_glob,   // [NSET][2][BSET][512]
    u32* __restrict__ cnt,        // [NSET][1024][CNT_STRIDE]
    float* __restrict__ enc_out,  // [64][KV_][512]
    float* __restrict__ h_n) {    // [64][512]
  const int tid = threadIdx.x;
  const int bid = blockIdx.x;
  const int xcd = bid & 7, jj = bid >> 3;
  const int s = xcd + 8 * (jj >> 4);
  const int wg = jj & 15;
  const int hb = wg * 32;          // hidden base of this WG's 32 units
  const int bg0 = s * BSET;

  const int rg = tid >> 4;         // 0..31 : row group (4 rows each)
  const int ksub = tid & 15;       // 0..15 : k sub-range (32 k's each)
  const int sw3 = ksub & 7;        // read-side XOR swizzle key

  __shared__ __align__(16) float hl[4 * 512];     // [b][k] linear
  __shared__ __align__(16) float xl[2][4 * 64];   // double-buffered [b][k]
  __shared__ __align__(16) float gb[128 * 4];     // [r_local][b]

  // ---- resident weights; register slot (j4,e) holds column ksub*32 + ((j4^sw3)*4+e)
  float wreg[4][32];
  float wxreg[4][4];
#pragma unroll
  for (int rr = 0; rr < 4; ++rr) {
    const int rl = rg * 4 + rr;                      // 0..127
    const int grow = ((rl >> 5) << 9) + hb + (rl & 31);
    const float* wrow = W_hh + (size_t)grow * 512 + (ksub << 5);
#pragma unroll
    for (int j4 = 0; j4 < 8; ++j4) {
      const int joff = ((j4 ^ sw3) << 2);
      const float4 wv = *(const float4*)(wrow + joff);
      wreg[rr][(j4 << 2) + 0] = wv.x;
      wreg[rr][(j4 << 2) + 1] = wv.y;
      wreg[rr][(j4 << 2) + 2] = wv.z;
      wreg[rr][(j4 << 2) + 3] = wv.w;
    }
    const float4 wx = *(const float4*)(W_ih + (size_t)grow * 64 + (ksub << 2));
    wxreg[rr][0] = wx.x; wxreg[rr][1] = wx.y; wxreg[rr][2] = wx.z; wxreg[rr][3] = wx.w;
  }

  // ---- update-thread state (tid<128: one (u,b) pair each) ----
  float bI = 0.f, bF = 0.f, bG = 0.f, bO = 0.f, cc = 0.f;
  const int ub = tid >> 2, bb = tid & 3;
  if (tid < 128) {
    const int r0 = hb + ub;
    bI = b_ih[r0] + b_hh[r0];
    bF = b_ih[512 + r0] + b_hh[512 + r0];
    bG = b_ih[1024 + r0] + b_hh[1024 + r0];
    bO = b_ih[1536 + r0] + b_hh[1536 + r0];
  }

  float* hg = h_glob + s * (2 * 2048);
  u32* cset = cnt + (size_t)s * 1024 * CNT_STRIDE;
  const float4* hl4 = (const float4*)hl;
  const int hbase = ksub << 3;

  // initial x load (t=0)
  if (tid < 256) {
    const int b = tid >> 6, k = tid & 63;
    xl[0][(b << 6) + k] = src[((size_t)(bg0 + b) * 1024 + 0) * 64 + k];
  }

  for (int t = 0; t < 1024; ++t) {
    // phase 1: wait for all WGs of the set to finish step t-1
    if (t > 0) {
      if (tid == 0) {
        while (__hip_atomic_load(&cset[(size_t)(t - 1) * CNT_STRIDE], __ATOMIC_ACQUIRE,
                                 __HIP_MEMORY_SCOPE_AGENT) < GSET) {
          __builtin_amdgcn_s_sleep(2);
        }
      }
      __syncthreads();  // B1
    }
    // phase 2: bulk h gather (coalesced, coherent) -> LDS (linear)
    if (t == 0) {
      ((float4*)hl)[tid] = make_float4(0.f, 0.f, 0.f, 0.f);
    } else {
      const float* hgp = hg + (((t - 1) & 1) << 11) + (tid << 2);
      ((float4*)hl)[tid] = load_f4_coherent(hgp);
    }
    __syncthreads();  // B2
    // x(t+1) prefetch — issue early, latency hides under compute
    float xnext = 0.f;
    if (tid < 256 && t + 1 < 1024) {
      const int b = tid >> 6, k = tid & 63;
      xnext = src[((size_t)(bg0 + b) * 1024 + (t + 1)) * 64 + k];
    }
    // phase 3: matvec (resident weights x LDS h), swizzled reads
    float acc[4][4];
#pragma unroll
    for (int rr = 0; rr < 4; ++rr)
#pragma unroll
      for (int b = 0; b < 4; ++b) acc[rr][b] = 0.f;
#pragma unroll
    for (int j4 = 0; j4 < 8; ++j4) {
      const int idx = hbase + (j4 ^ sw3);
      const float4 h0 = hl4[idx];
      const float4 h1 = hl4[128 + idx];
      const float4 h2 = hl4[256 + idx];
      const float4 h3 = hl4[384 + idx];
#pragma unroll
      for (int rr = 0; rr < 4; ++rr) {
        const float w0 = wreg[rr][(j4 << 2) + 0], w1 = wreg[rr][(j4 << 2) + 1];
        const float w2 = wreg[rr][(j4 << 2) + 2], w3 = wreg[rr][(j4 << 2) + 3];
        acc[rr][0] = fmaf(w0, h0.x, fmaf(w1, h0.y, fmaf(w2, h0.z, fmaf(w3, h0.w, acc[rr][0]))));
        acc[rr][1] = fmaf(w0, h1.x, fmaf(w1, h1.y, fmaf(w2, h1.z, fmaf(w3, h1.w, acc[rr][1]))));
        acc[rr][2] = fmaf(w0, h2.x, fmaf(w1, h2.y, fmaf(w2, h2.z, fmaf(w3, h2.w, acc[rr][2]))));
        acc[rr][3] = fmaf(w0, h3.x, fmaf(w1, h3.y, fmaf(w2, h3.z, fmaf(w3, h3.w, acc[rr][3]))));
      }
    }
    {
      const float4* xl4p = (const float4*)xl[t & 1];
      const float4 x0 = xl4p[ksub];
      const float4 x1 = xl4p[16 + ksub];
      const float4 x2 = xl4p[32 + ksub];
      const float4 x3 = xl4p[48 + ksub];
#pragma unroll
      for (int rr = 0; rr < 4; ++rr) {
        const float w0 = wxreg[rr][0], w1 = wxreg[rr][1], w2 = wxreg[rr][2], w3 = wxreg[rr][3];
        acc[rr][0] = fmaf(w0, x0.x, fmaf(w1, x0.y, fmaf(w2, x0.z, fmaf(w3, x0.w, acc[rr][0]))));
        acc[rr][1] = fmaf(w0, x1.x, fmaf(w1, x1.y, fmaf(w2, x1.z, fmaf(w3, x1.w, acc[rr][1]))));
        acc[rr][2] = fmaf(w0, x2.x, fmaf(w1, x2.y, fmaf(w2, x2.z, fmaf(w3, x2.w, acc[rr][2]))));
        acc[rr][3] = fmaf(w0, x3.x, fmaf(w1, x3.y, fmaf(w2, x3.z, fmaf(w3, x3.w, acc[rr][3]))));
      }
    }
    // reduce over 16 k-lanes
#pragma unroll
    for (int off = 1; off < 16; off <<= 1) {
#pragma unroll
      for (int rr = 0; rr < 4; ++rr) {
#pragma unroll
        for (int b = 0; b < 4; ++b)
          acc[rr][b] += __shfl_xor(acc[rr][b], off, 16);
      }
    }
    if (ksub == 0) {
#pragma unroll
      for (int rr = 0; rr < 4; ++rr)
        ((float4*)gb)[rg * 4 + rr] = make_float4(acc[rr][0], acc[rr][1], acc[rr][2], acc[rr][3]);
    }
    __syncthreads();  // B3
    // phase 4a: stash prefetched x
    if (tid < 256 && t + 1 < 1024) xl[(t + 1) & 1][tid] = xnext;
    // phase 4b: gate update + h publication
    if (tid < 128) {
      const float gi = gb[(ub) * 4 + bb] + bI;
      const float gf = gb[(32 + ub) * 4 + bb] + bF;
      const float gg = gb[(64 + ub) * 4 + bb] + bG;
      const float go = gb[(96 + ub) * 4 + bb] + bO;
      const float iv = 1.f / (1.f + expf(-gi));
      const float fv = 1.f / (1.f + expf(-gf));
      const float gv = tanhf(gg);
      const float ov = 1.f / (1.f + expf(-go));
      cc = fv * cc + iv * gv;
      const float hv = ov * tanhf(cc);
      store_f_coherent(&hg[((t & 1) << 11) + (bb << 9) + hb + ub], hv);
      if (t < KV_) enc_out[((size_t)(bg0 + bb) * KV_ + t) * 512 + hb + ub] = hv;
      if (t == 1023) h_n[(size_t)(bg0 + bb) * 512 + hb + ub] = hv;
    }
    asm volatile("s_waitcnt vmcnt(0)" ::: "memory");  // drain h stores (every wave)
    __syncthreads();  // B4
    // phase 5: arrive
    if (t < 1023 && tid == 0) {
      __hip_atomic_fetch_add(&cset[(size_t)t * CNT_STRIDE], 1u, __ATOMIC_RELEASE,
                             __HIP_MEMORY_SCOPE_AGENT);
    }
  }
}

// ---------------- panel GEMM (fp32 in, bf16 out) ----------------
__global__ __launch_bounds__(256) void gemm_panel(
    const float* __restrict__ A, int M, int nseg, int shifted,
    const float* __restrict__ Bm, const float* __restrict__ bias,
    u16* __restrict__ C) {
  __shared__ float As[16][72];
  __shared__ float Bs[16][64];
  const int tid = threadIdx.x;
  const int nx = blockIdx.x, my = blockIdx.y;
  const int tx = tid & 15, ty = tid >> 4;
  const int m0 = ty * 4, n0 = tx * 4;
  const int lr = tid >> 2, lc = (tid & 3) * 4;
  const int kr = tid >> 4, nc = (tid & 15) * 4;
  float acc[4][4] = {};
  const int KK = nseg * 512;
  const int rA = my * 64 + lr;
  const int tloc = rA % KV_;
  for (int kk = 0; kk < KK; kk += 16) {
    const int seg = kk >> 9, k0 = kk & 511;
    float4 av = make_float4(0.f, 0.f, 0.f, 0.f);
    if (rA < M) {
      int arow = rA, valid = 1;
      if (shifted) { arow = rA + seg - 2; valid = (tloc + seg - 2) >= 0; }
      if (valid) av = *(const float4*)&A[(size_t)arow * 512 + k0 + lc];
    }
    As[lc + 0][lr] = av.x; As[lc + 1][lr] = av.y;
    As[lc + 2][lr] = av.z; As[lc + 3][lr] = av.w;
    *(float4*)&Bs[kr][nc] = *(const float4*)&Bm[(size_t)(kk + kr) * 512 + nx * 64 + nc];
    __syncthreads();
#pragma unroll
    for (int k = 0; k < 16; ++k) {
      float4 A4 = *(const float4*)&As[k][m0];
      float4 B4 = *(const float4*)&Bs[k][n0];
      float ar[4] = {A4.x, A4.y, A4.z, A4.w};
      float br[4] = {B4.x, B4.y, B4.z, B4.w};
#pragma unroll
      for (int ii = 0; ii < 4; ++ii)
#pragma unroll
        for (int jj = 0; jj < 4; ++jj)
          acc[ii][jj] = fmaf(ar[ii], br[jj], acc[ii][jj]);
    }
    __syncthreads();
  }
#pragma unroll
  for (int ii = 0; ii < 4; ++ii) {
    int r = my * 64 + m0 + ii;
    if (r < M) {
#pragma unroll
      for (int jj = 0; jj < 4; ++jj) {
        int col = nx * 64 + n0 + jj;
        float v = acc[ii][jj] + (bias ? bias[col] : 0.f);
        C[(size_t)r * 512 + col] = f2bf(v);
      }
    }
  }
}

// ---------------- attention + head ----------------
__global__ __launch_bounds__(256) void attn_final(
    const u16* __restrict__ Qp, const u16* __restrict__ Kp, const u16* __restrict__ Vp,
    const float* __restrict__ h_n, const float* __restrict__ Wfc,
    const float* __restrict__ catW, const float* __restrict__ catb,
    const float* __restrict__ outW, float* __restrict__ out) {
  const int b = blockIdx.x, tid = threadIdx.x;
  __shared__ float sc[8 * KV_];
  __shared__ float ctx[512];
  __shared__ float av[512];
  __shared__ float ha[64];
  __shared__ uint4 qs[64];
  if (tid < 64) qs[tid] = ((const uint4*)(Qp + (size_t)b * 512))[tid];
  __syncthreads();
  for (int idx = tid; idx < 8 * KV_; idx += 256) {
    int h = idx / KV_, t = idx % KV_;
    const uint4* kr4 = (const uint4*)(Kp + ((size_t)(b * KV_ + t)) * 512 + h * 64);
    float s = 0.f;
#pragma unroll
    for (int u = 0; u < 8; ++u) {
      uint4 kv = kr4[u]; uint4 qv = qs[h * 8 + u];
      s += blo(kv.x) * blo(qv.x) + bhi(kv.x) * bhi(qv.x)
         + blo(kv.y) * blo(qv.y) + bhi(kv.y) * bhi(qv.y)
         + blo(kv.z) * blo(qv.z) + bhi(kv.z) * bhi(qv.z)
         + blo(kv.w) * blo(qv.w) + bhi(kv.w) * bhi(qv.w);
    }
    sc[h * KV_ + t] = s * 0.125f;
  }
  __syncthreads();
  {
    int h = tid >> 5, l = tid & 31;
    float m = -1e30f;
    for (int t = l; t < KV_; t += 32) m = fmaxf(m, sc[h * KV_ + t]);
    for (int o = 16; o; o >>= 1) m = fmaxf(m, __shfl_xor(m, o, 32));
    float sum = 0.f;
    for (int t = l; t < KV_; t += 32) { float e = expf(sc[h * KV_ + t] - m); sc[h * KV_ + t] = e; sum += e; }
    for (int o = 16; o; o >>= 1) sum += __shfl_xor(sum, o, 32);
    float inv = 1.f / sum;
    for (int t = l; t < KV_; t += 32) sc[h * KV_ + t] *= inv;
  }
  __syncthreads();
  for (int j = tid; j < 512; j += 256) {
    int h = j >> 6, d = j & 63;
    const u16* vp = Vp + (size_t)(b * KV_) * 512 + h * 64 + d;
    float a = 0.f;
    for (int t = 0; t < KV_; ++t)
      a = fmaf(sc[h * KV_ + t], blo((u32)vp[(size_t)t * 512]), a);
    ctx[j] = a;
  }
  __syncthreads();
  for (int j = tid; j < 512; j += 256) {
    float a = 0.f;
    for (int i = 0; i < 512; ++i) a = fmaf(ctx[i], Wfc[(size_t)i * 512 + j], a);
    av[j] = a;
  }
  __syncthreads();
  if (tid < 64) {
    float a = catb[tid];
    const float* hb = h_n + (size_t)b * 512;
    for (int i = 0; i < 512; ++i) a = fmaf(hb[i], catW[i * 64 + tid], a);
    for (int i = 0; i < 512; ++i) a = fmaf(av[i], catW[(512 + i) * 64 + tid], a);
    ha[tid] = a;
  }
  __syncthreads();
  if (tid < 64) {
    float v = ha[tid] * outW[tid];
    for (int o = 32; o; o >>= 1) v += __shfl_xor(v, o, 64);
    if (tid == 0) out[b] = v;
  }
}

extern "C" void kernel_launch(void* const* d_in, const int* in_sizes, int n_in,
                              void* d_out, int out_size, void* d_ws, size_t ws_size,
                              hipStream_t stream) {
  const float* src   = (const float*)d_in[0];
  const float* W_ih  = (const float*)d_in[2];
  const float* W_hh  = (const float*)d_in[3];
  const float* b_ih  = (const float*)d_in[4];
  const float* b_hh  = (const float*)d_in[5];
  const float* convw = (const float*)d_in[6];
  const float* convb = (const float*)d_in[7];
  const float* Wq    = (const float*)d_in[8];
  const float* Wk    = (const float*)d_in[9];
  const float* Wv    = (const float*)d_in[10];
  const float* Wfc   = (const float*)d_in[11];
  const float* catW  = (const float*)d_in[12];
  const float* catb  = (const float*)d_in[13];
  const float* outW  = (const float*)d_in[14];
  float* out = (float*)d_out;

  char* w = (char*)d_ws;
  float* Beff  = (float*)w;  w += (size_t)3 * 512 * 512 * 4;
  float* Qeff  = (float*)w;  w += (size_t)512 * 512 * 4;
  float* Veff  = (float*)w;  w += (size_t)512 * 512 * 4;
  float* kb    = (float*)w;  w += 512 * 4;
  float* qb    = (float*)w;  w += 512 * 4;
  float* h_n   = (float*)w;  w += (size_t)64 * 512 * 4;
  float* enc   = (float*)w;  w += (size_t)64 * KV_ * 512 * 4;
  u16*   Kp    = (u16*)w;    w += (size_t)64 * KV_ * 512 * 2;
  u16*   Vp    = (u16*)w;    w += (size_t)64 * KV_ * 512 * 2;
  u16*   Qp    = (u16*)w;    w += (size_t)64 * 512 * 2;
  float* h_glob = (float*)w; w += (size_t)NSET * 2 * 2048 * 4;
  u32*   cnt   = (u32*)w;    w += (size_t)NSET * 1024 * CNT_STRIDE * 4;

  veff_kernel<<<1024, 256, 0, stream>>>(Wv, Veff);
  eff_mat<<<512, 512, 0, stream>>>(convw + 0, 1536, 3, Wk + 262144, nullptr, Beff);
  eff_mat<<<512, 512, 0, stream>>>(convw + 1, 1536, 3, Wk + 262144, nullptr, Beff + 262144);
  eff_mat<<<512, 512, 0, stream>>>(convw + 2, 1536, 3, Wk + 262144, Wk, Beff + 524288);
  eff_mat<<<512, 512, 0, stream>>>(convw + 2, 1536, 3, Wq + 262144, Wq, Qeff);
  eff_mat<<<1, 512, 0, stream>>>(convb, 1, 0, Wk + 262144, nullptr, kb);
  eff_mat<<<1, 512, 0, stream>>>(convb, 1, 0, Wq + 262144, nullptr, qb);

  hipMemsetAsync((void*)cnt, 0, (size_t)NSET * 1024 * CNT_STRIDE * 4, stream);
  {
    const float* a_src = src; const float* a_wih = W_ih; const float* a_whh = W_hh;
    const float* a_bih = b_ih; const float* a_bhh = b_hh;
    float* a_hg = h_glob; u32* a_cnt = cnt; float* a_enc = enc; float* a_hn = h_n;
    void* args[] = {(void*)&a_src, (void*)&a_wih, (void*)&a_whh, (void*)&a_bih,
                    (void*)&a_bhh, (void*)&a_hg, (void*)&a_cnt, (void*)&a_enc, (void*)&a_hn};
    hipLaunchCooperativeKernel(lstm_sync, dim3(256), dim3(512), args, 0, stream);
  }

  gemm_panel<<<dim3(8, KV_), 256, 0, stream>>>(enc, 64 * KV_, 3, 1, Beff, kb, Kp);
  gemm_panel<<<dim3(8, KV_), 256, 0, stream>>>(enc, 64 * KV_, 1, 0, Veff, nullptr, Vp);
  gemm_panel<<<dim3(8, 1), 256, 0, stream>>>(h_n, 64, 1, 0, Qeff, qb, Qp);
  attn_final<<<64, 256, 0, stream>>>(Qp, Kp, Vp, h_n, Wfc, catW, catb, outW, out);
}